// Round 20
// baseline (96.447 us; speedup 1.0000x reference)
//
#include <hip/hip_runtime.h>
#include <math.h>

#define BATCH 32
#define NN 1024
#define FF 128
#define HH 128
#define NODES 32   // nodes per block in kernel A
#define PROW 72    // padded P strip row (bf16): 144B = 9 x 16B, spreads banks

typedef __attribute__((ext_vector_type(8))) short short8v;   // 8 bf16
typedef __attribute__((ext_vector_type(4))) float f32x4;     // MFMA acc

__device__ __forceinline__ unsigned short f2bf(float f) {    // RNE f32->bf16
    unsigned u = __float_as_uint(f);
    u += 0x7fffu + ((u >> 16) & 1u);
    return (unsigned short)(u >> 16);
}

// ---------------- Kernel A: h = X@W -> g (MFMA-B-fragment-swizzled bf16);
// a_self / a_neigh scalars.  g[(batch,kc,ct,lane=kg*16+li,e)] = h[kc*32+kg*8+e][ct*16+li]
__global__ __launch_bounds__(128) void gat_hidden(
    const float* __restrict__ X,      // [B,N,F]
    const float* __restrict__ W,      // [F,H]
    const float* __restrict__ Wself,  // [H]
    const float* __restrict__ Wneigh, // [H]
    unsigned short* __restrict__ g,   // [B][32 kc][8 ct][64 lane][8] bf16
    float* __restrict__ a_self,       // [B*N]
    float* __restrict__ a_neigh)      // [B*N]
{
    __shared__ float xs[NODES][FF];      // 16 KB
    __shared__ float hs[NODES][HH + 1];  // 16.5 KB
    const int tid = threadIdx.x;
    const long base_node = (long)blockIdx.x * NODES;
    const int batch = (int)(base_node >> 10);
    const int kc = (int)((base_node & 1023) >> 5);   // 32-node chunk index

    const float4* X4 = (const float4*)(X + base_node * FF);
    float4* xs4 = (float4*)&xs[0][0];
#pragma unroll
    for (int k = 0; k < (NODES * FF) / (4 * 128); k++)
        xs4[k * 128 + tid] = X4[k * 128 + tid];
    __syncthreads();

    float acc[NODES];
#pragma unroll
    for (int n = 0; n < NODES; n++) acc[n] = 0.f;
    const int c = tid;
    for (int fq = 0; fq < FF / 4; fq++) {
        const float w0 = W[(4 * fq + 0) * HH + c];
        const float w1 = W[(4 * fq + 1) * HH + c];
        const float w2 = W[(4 * fq + 2) * HH + c];
        const float w3 = W[(4 * fq + 3) * HH + c];
#pragma unroll
        for (int n = 0; n < NODES; n++) {
            const float4 x4 = *(const float4*)&xs[n][4 * fq];
            acc[n] += x4.x * w0 + x4.y * w1 + x4.z * w2 + x4.w * w3;
        }
    }
    {
        const int ct = c >> 4, li = c & 15;
        unsigned short* gb = g + ((((size_t)batch * 32 + kc) * 8 + ct) * 64) * 8;
        union { uint4 q; unsigned short u[8]; } pk;
#pragma unroll
        for (int kg = 0; kg < 4; kg++) {
#pragma unroll
            for (int e = 0; e < 8; e++) pk.u[e] = f2bf(acc[kg * 8 + e]);
            *(uint4*)(gb + (kg * 16 + li) * 8) = pk.q;
        }
    }
#pragma unroll
    for (int n = 0; n < NODES; n++) hs[n][c] = acc[n];
    __syncthreads();

    if (tid < 2 * NODES) {
        const int n = tid & (NODES - 1);
        const float* wvp = (tid < NODES) ? Wself : Wneigh;
        float s = 0.f;
        for (int cc = 0; cc < HH; cc++) s += hs[n][cc] * wvp[cc];
        if (tid < NODES) a_self[base_node + n] = s;
        else             a_neigh[base_node + n] = s;
    }
}

// ---------------- Kernel B: P@H via MFMA, WAVE-PRIVATE tiles, ZERO barriers.
// Wave job = 16-row tile x 64 out-cols (4 ct groups) x full K=1024.
// Sibling waves (ct-halves) duplicate staging; adj reuse L2-hits.
// Per iter (k-chunk 64): coalesced adj/a_neigh loads -> exp/pack -> ds_write
// (wave-private strip) -> ds_read A-frag (intra-wave lgkmcnt only) -> 8 MFMA.
// Numerics identical to R19: unnormalized exp, rowsum of bf16-ROUNDED p.
__global__ __launch_bounds__(256) void gat_attend(
    const float* __restrict__ adj,     // [B,N,N]
    const float* __restrict__ mask,    // [B,N]
    const unsigned short* __restrict__ g, // swizzled bf16 h
    const float* __restrict__ a_self,  // [B*N]
    const float* __restrict__ a_neigh, // [B*N]
    const float* __restrict__ bvec,    // [H]
    float* __restrict__ out)           // [B,N,H]
{
    const int tid = threadIdx.x;
    const int lane = tid & 63;
    const int wv = tid >> 6;
    // 1024 blocks; XCD x owns 4 batches; block covers 2 tiles x 2 ct-halves
    const int b = blockIdx.x;
    const int xcd = b & 7;
    const int rest = b >> 3;                     // 0..127
    const int batch = xcd * 4 + (rest >> 5);
    const int tile = (rest & 31) * 2 + (wv >> 1);   // 0..63
    const int cg = (wv & 1) * 4;                 // ct-group base (0 or 4)
    const int r0 = batch * NN + tile * 16;       // 768 % 16 == 0: tile uniform

    __shared__ unsigned short P[4][2][16 * PROW];   // per-wave dbuf strips, 18 KB
    unsigned short (*pew)[16 * PROW] = P[wv];

    const int lrow = lane >> 2;                  // staging row 0..15
    const int lcq = lane & 3;                    // col quarter (16 cols each)

    if (mask[r0] == 0.f) {                       // wave-uniform; no barriers -> safe
        float4* o4 = (float4*)(out + (size_t)(r0 + lrow) * HH + cg * 16 + lcq * 16);
        o4[0] = make_float4(0.f, 0.f, 0.f, 0.f);
        o4[1] = make_float4(0.f, 0.f, 0.f, 0.f);
        o4[2] = make_float4(0.f, 0.f, 0.f, 0.f);
        o4[3] = make_float4(0.f, 0.f, 0.f, 0.f);
        return;
    }

    const float4* arow4 = (const float4*)(adj + (size_t)(r0 + lrow) * NN);
    const float4* an4p  = (const float4*)(a_neigh + (size_t)batch * NN);
    const float asl = a_self[r0 + lrow];
    const unsigned short* gb = g + (size_t)batch * 131072;   // 32*8*64*8

    float rs = 0.f;
    float4 pf_a0, pf_a1, pf_a2, pf_a3, pf_n0, pf_n1, pf_n2, pf_n3;

#define LOADS(t)                                              \
    {                                                         \
        const int o = (t) * 16 + lcq * 4;                     \
        pf_a0 = arow4[o];     pf_a1 = arow4[o + 1];           \
        pf_a2 = arow4[o + 2]; pf_a3 = arow4[o + 3];           \
        pf_n0 = an4p[o];      pf_n1 = an4p[o + 1];            \
        pf_n2 = an4p[o + 2];  pf_n3 = an4p[o + 3];            \
    }
#define EW4(a4, n4, off)                                                             \
    {                                                                                \
        float x, p;                                                                  \
        x = asl + n4.x; p = (a4.x > 0.f) ? __expf(fmaxf(x, 0.2f * x)) : 0.f;         \
        pk.u[(off) + 0] = f2bf(p); rs += __uint_as_float((unsigned)pk.u[(off) + 0] << 16); \
        x = asl + n4.y; p = (a4.y > 0.f) ? __expf(fmaxf(x, 0.2f * x)) : 0.f;         \
        pk.u[(off) + 1] = f2bf(p); rs += __uint_as_float((unsigned)pk.u[(off) + 1] << 16); \
        x = asl + n4.z; p = (a4.z > 0.f) ? __expf(fmaxf(x, 0.2f * x)) : 0.f;         \
        pk.u[(off) + 2] = f2bf(p); rs += __uint_as_float((unsigned)pk.u[(off) + 2] << 16); \
        x = asl + n4.w; p = (a4.w > 0.f) ? __expf(fmaxf(x, 0.2f * x)) : 0.f;         \
        pk.u[(off) + 3] = f2bf(p); rs += __uint_as_float((unsigned)pk.u[(off) + 3] << 16); \
    }
#define EXPWRITE(buf)                                                 \
    {                                                                 \
        union { unsigned short u[16]; uint4 q[2]; } pk;               \
        EW4(pf_a0, pf_n0, 0)  EW4(pf_a1, pf_n1, 4)                    \
        EW4(pf_a2, pf_n2, 8)  EW4(pf_a3, pf_n3, 12)                   \
        uint4* dst = (uint4*)&pew[buf][lrow * PROW + lcq * 16];       \
        dst[0] = pk.q[0]; dst[1] = pk.q[1];                           \
    }

    f32x4 acc[4];
#pragma unroll
    for (int ct = 0; ct < 4; ct++)
#pragma unroll
        for (int i = 0; i < 4; i++) acc[ct][i] = 0.f;

    const int li = lane & 15;
    const int kg8 = (lane >> 4) * 8;

    LOADS(0)
    for (int it = 0; it < 16; ++it) {
        const int cur = it & 1;
        EXPWRITE(cur)                        // ds_write own strip
        if (it < 15) LOADS(it + 1)           // next chunk flies under MFMA
#pragma unroll
        for (int kcl = 0; kcl < 2; kcl++) {  // ds_read waits via lgkmcnt (no barrier)
            const short8v af = *(const short8v*)&pew[cur][li * PROW + kcl * 32 + kg8];
            const int kcG = it * 2 + kcl;
#pragma unroll
            for (int ctl = 0; ctl < 4; ctl++) {
                const short8v bf = *(const short8v*)(gb + ((size_t)(kcG * 8 + cg + ctl) * 64 + lane) * 8);
                acc[ctl] = __builtin_amdgcn_mfma_f32_16x16x32_bf16(af, bf, acc[ctl], 0, 0, 0);
            }
        }
    }

    // rowsum: quad lanes (same lrow) hold disjoint col partials
    rs += __shfl_xor(rs, 1);
    rs += __shfl_xor(rs, 2);                 // lanes 4*lrow.. hold row total
    float invv[4];
#pragma unroll
    for (int i = 0; i < 4; i++)
        invv[i] = 1.f / __shfl(rs, ((lane >> 4) * 4 + i) * 4);

#pragma unroll
    for (int ctl = 0; ctl < 4; ctl++) {
        const float bv = bvec[(cg + ctl) * 16 + li];
#pragma unroll
        for (int i = 0; i < 4; i++) {
            const int r = (lane >> 4) * 4 + i;   // D row
            out[(size_t)(r0 + r) * HH + (cg + ctl) * 16 + li] =
                acc[ctl][i] * invv[i] + bv;
        }
    }
#undef LOADS
#undef EW4
#undef EXPWRITE
}

extern "C" void kernel_launch(void* const* d_in, const int* in_sizes, int n_in,
                              void* d_out, int out_size, void* d_ws, size_t ws_size,
                              hipStream_t stream) {
    const float* X      = (const float*)d_in[0];  // M_features [B,N,F]
    const float* adj    = (const float*)d_in[1];  // M_adjacency [B,N,N]
    const float* mask   = (const float*)d_in[2];  // [B,N]
    const float* W      = (const float*)d_in[3];  // [F,H]
    const float* bvec   = (const float*)d_in[4];  // [H]
    const float* Wself  = (const float*)d_in[5];  // [H,1]
    const float* Wneigh = (const float*)d_in[6];  // [H,1]
    float* out = (float*)d_out;

    char* wsb = (char*)d_ws;
    unsigned short* g = (unsigned short*)wsb;                // 8 MB
    float* a_self  = (float*)(wsb + (size_t)BATCH * NN * HH * 2);
    float* a_neigh = a_self + (size_t)BATCH * NN;

    gat_hidden<<<(BATCH * NN) / NODES, 128, 0, stream>>>(
        X, W, Wself, Wneigh, g, a_self, a_neigh);
    gat_attend<<<1024, 256, 0, stream>>>(
        adj, mask, g, a_self, a_neigh, bvec, out);
}

// Round 21
// 57.974 us; speedup vs baseline: 1.6636x; 1.6636x over previous
//
#include <hip/hip_runtime.h>
#include <math.h>

#define BATCH 32
#define NN 1024
#define FF 128
#define HH 128
#define NODES 32   // nodes per block in kernel A
#define PROW 72    // padded P-tile row (bf16): 144B, spreads banks

typedef __attribute__((ext_vector_type(8))) short short8v;   // 8 bf16
typedef __attribute__((ext_vector_type(4))) float f32x4;     // MFMA acc

__device__ __forceinline__ unsigned short f2bf(float f) {    // RNE f32->bf16
    unsigned u = __float_as_uint(f);
    u += 0x7fffu + ((u >> 16) & 1u);
    return (unsigned short)(u >> 16);
}

// ---------------- Kernel A: h = X@W -> g (MFMA-B-fragment-swizzled bf16);
// a_self / a_neigh scalars.  g[(batch,kc,ct,lane=kg*16+li,e)] = h[kc*32+kg*8+e][ct*16+li]
__global__ __launch_bounds__(128) void gat_hidden(
    const float* __restrict__ X,      // [B,N,F]
    const float* __restrict__ W,      // [F,H]
    const float* __restrict__ Wself,  // [H]
    const float* __restrict__ Wneigh, // [H]
    unsigned short* __restrict__ g,   // [B][32 kc][8 ct][64 lane][8] bf16
    float* __restrict__ a_self,       // [B*N]
    float* __restrict__ a_neigh)      // [B*N]
{
    __shared__ float xs[NODES][FF];      // 16 KB
    __shared__ float hs[NODES][HH + 1];  // 16.5 KB
    const int tid = threadIdx.x;
    const long base_node = (long)blockIdx.x * NODES;
    const int batch = (int)(base_node >> 10);
    const int kc = (int)((base_node & 1023) >> 5);   // 32-node chunk index

    const float4* X4 = (const float4*)(X + base_node * FF);
    float4* xs4 = (float4*)&xs[0][0];
#pragma unroll
    for (int k = 0; k < (NODES * FF) / (4 * 128); k++)
        xs4[k * 128 + tid] = X4[k * 128 + tid];
    __syncthreads();

    float acc[NODES];
#pragma unroll
    for (int n = 0; n < NODES; n++) acc[n] = 0.f;
    const int c = tid;
    for (int fq = 0; fq < FF / 4; fq++) {
        const float w0 = W[(4 * fq + 0) * HH + c];
        const float w1 = W[(4 * fq + 1) * HH + c];
        const float w2 = W[(4 * fq + 2) * HH + c];
        const float w3 = W[(4 * fq + 3) * HH + c];
#pragma unroll
        for (int n = 0; n < NODES; n++) {
            const float4 x4 = *(const float4*)&xs[n][4 * fq];
            acc[n] += x4.x * w0 + x4.y * w1 + x4.z * w2 + x4.w * w3;
        }
    }
    {
        const int ct = c >> 4, li = c & 15;
        unsigned short* gb = g + ((((size_t)batch * 32 + kc) * 8 + ct) * 64) * 8;
        union { uint4 q; unsigned short u[8]; } pk;
#pragma unroll
        for (int kg = 0; kg < 4; kg++) {
#pragma unroll
            for (int e = 0; e < 8; e++) pk.u[e] = f2bf(acc[kg * 8 + e]);
            *(uint4*)(gb + (kg * 16 + li) * 8) = pk.q;
        }
    }
#pragma unroll
    for (int n = 0; n < NODES; n++) hs[n][c] = acc[n];
    __syncthreads();

    if (tid < 2 * NODES) {
        const int n = tid & (NODES - 1);
        const float* wvp = (tid < NODES) ? Wself : Wneigh;
        float s = 0.f;
        for (int cc = 0; cc < HH; cc++) s += hs[n][cc] * wvp[cc];
        if (tid < NODES) a_self[base_node + n] = s;
        else             a_neigh[base_node + n] = s;
    }
}

// ---------------- Kernel B: fused P@H, 64-row tiles, 8 waves, full K.
// Wave = ONE ct column (16 out-cols) x all four 16-row tiles -> each B-load
// feeds 4 MFMAs and is loaded by exactly one wave (B traffic 512->128 MB).
// Staging (R19-proven): 512 thr stage 64 rows x 64 cols/iter, 8 exps/thread.
// T14: next iter's loads issued before the MFMA phase. Unnormalized exp;
// rowsum of bf16-ROUNDED p; normalize+bias in epilogue; no partials.
__global__ __launch_bounds__(512) void gat_attend(
    const float* __restrict__ adj,     // [B,N,N]
    const float* __restrict__ mask,    // [B,N]
    const unsigned short* __restrict__ g, // swizzled bf16 h
    const float* __restrict__ a_self,  // [B*N]
    const float* __restrict__ a_neigh, // [B*N]
    const float* __restrict__ bvec,    // [H]
    float* __restrict__ out)           // [B,N,H]
{
    const int tid = threadIdx.x;
    const int lane = tid & 63;
    const int wv = tid >> 6;                 // 0..7 = ct column
    // 512 blocks; XCD x owns 4 batches
    const int b = blockIdx.x;
    const int xcd = b & 7;
    const int rest = b >> 3;                 // 0..63
    const int batch = xcd * 4 + (rest >> 4);
    const int tile = rest & 15;              // 0..15 (64-row tiles)
    const int r0 = batch * NN + tile * 64;   // 768 % 64 == 0: tile uniform

    if (mask[r0] == 0.f) {                   // invalid tile: zero-fill out
        float4* o4 = (float4*)(out + (size_t)r0 * HH);
#pragma unroll
        for (int k = 0; k < 4; k++)
            o4[k * 512 + tid] = make_float4(0.f, 0.f, 0.f, 0.f);
        return;
    }

    __shared__ unsigned short P[2][64 * PROW];   // 18432 B
    __shared__ float rtot[64];                   // 256 B

    // staging: thread owns row srow (tid>>3), float4-cols c8 and c8+8
    const int srow = tid >> 3;               // 0..63
    const int c8 = tid & 7;
    const float4* arow = (const float4*)(adj + (size_t)(r0 + srow) * NN);
    const float4* anp = (const float4*)(a_neigh + (size_t)batch * NN);
    const float asl = a_self[r0 + srow];
    const unsigned short* gb = g + (size_t)batch * 131072;   // 32*8*64*8

    float rs = 0.f;
    float4 pf_a0, pf_a1, pf_n0, pf_n1;       // in-flight stage registers (T14)

#define LOADS(t)                                      \
    {                                                 \
        const int o = (t) * 16 + c8;                  \
        pf_a0 = arow[o];     pf_a1 = arow[o + 8];     \
        pf_n0 = anp[o];      pf_n1 = anp[o + 8];      \
    }
#define EW(a4, n4, elem0, buf)                                                       \
    {                                                                                \
        union { unsigned short u[4]; uint2 q; } wq;                                  \
        float x, p;                                                                  \
        x = asl + n4.x; p = (a4.x > 0.f) ? __expf(fmaxf(x, 0.2f * x)) : 0.f;         \
        wq.u[0] = f2bf(p); rs += __uint_as_float((unsigned)wq.u[0] << 16);           \
        x = asl + n4.y; p = (a4.y > 0.f) ? __expf(fmaxf(x, 0.2f * x)) : 0.f;         \
        wq.u[1] = f2bf(p); rs += __uint_as_float((unsigned)wq.u[1] << 16);           \
        x = asl + n4.z; p = (a4.z > 0.f) ? __expf(fmaxf(x, 0.2f * x)) : 0.f;         \
        wq.u[2] = f2bf(p); rs += __uint_as_float((unsigned)wq.u[2] << 16);           \
        x = asl + n4.w; p = (a4.w > 0.f) ? __expf(fmaxf(x, 0.2f * x)) : 0.f;         \
        wq.u[3] = f2bf(p); rs += __uint_as_float((unsigned)wq.u[3] << 16);           \
        *(uint2*)&P[buf][srow * PROW + (elem0)] = wq.q;                              \
    }
#define EXPWRITE(buf)                        \
    {                                        \
        EW(pf_a0, pf_n0, c8 * 4, buf)        \
        EW(pf_a1, pf_n1, 32 + c8 * 4, buf)   \
    }

    f32x4 acc[4];                            // one per 16-row tile
#pragma unroll
    for (int rt = 0; rt < 4; rt++)
#pragma unroll
        for (int i = 0; i < 4; i++) acc[rt][i] = 0.f;

    // prologue
    LOADS(0)
    EXPWRITE(0)
    __syncthreads();

    const int li = lane & 15;
    const int kg8 = (lane >> 4) * 8;
    const float bv = bvec[wv * 16 + li];

    for (int it = 0; it < 16; ++it) {
        const int cur = it & 1;
        if (it < 15) LOADS(it + 1)           // T14: issue early, consume late
#pragma unroll
        for (int kcl = 0; kcl < 2; kcl++) {
            const int kcG = it * 2 + kcl;
            const short8v bf = *(const short8v*)(gb + ((size_t)(kcG * 8 + wv) * 64 + lane) * 8);
#pragma unroll
            for (int rt = 0; rt < 4; rt++) { // one B-load feeds 4 MFMAs
                const short8v af = *(const short8v*)&P[cur][(rt * 16 + li) * PROW + kcl * 32 + kg8];
                acc[rt] = __builtin_amdgcn_mfma_f32_16x16x32_bf16(af, bf, acc[rt], 0, 0, 0);
            }
        }
        if (it < 15) EXPWRITE(cur ^ 1)       // stage latency hidden under MFMA
        __syncthreads();
    }

    // rowsum: 8 threads per row (same wave, consecutive lanes) hold partials
    rs += __shfl_xor(rs, 1);
    rs += __shfl_xor(rs, 2);
    rs += __shfl_xor(rs, 4);
    if ((lane & 7) == 0) rtot[srow] = rs;
    __syncthreads();

    // epilogue: wave wv owns out-cols wv*16..+15 for all 64 rows
#pragma unroll
    for (int rt = 0; rt < 4; rt++) {
#pragma unroll
        for (int i = 0; i < 4; i++) {
            const int r = rt * 16 + (lane >> 4) * 4 + i;
            const float inv = 1.f / rtot[r];
            out[(size_t)(r0 + r) * HH + wv * 16 + li] = acc[rt][i] * inv + bv;
        }
    }
#undef LOADS
#undef EW
#undef EXPWRITE
}

extern "C" void kernel_launch(void* const* d_in, const int* in_sizes, int n_in,
                              void* d_out, int out_size, void* d_ws, size_t ws_size,
                              hipStream_t stream) {
    const float* X      = (const float*)d_in[0];  // M_features [B,N,F]
    const float* adj    = (const float*)d_in[1];  // M_adjacency [B,N,N]
    const float* mask   = (const float*)d_in[2];  // [B,N]
    const float* W      = (const float*)d_in[3];  // [F,H]
    const float* bvec   = (const float*)d_in[4];  // [H]
    const float* Wself  = (const float*)d_in[5];  // [H,1]
    const float* Wneigh = (const float*)d_in[6];  // [H,1]
    float* out = (float*)d_out;

    char* wsb = (char*)d_ws;
    unsigned short* g = (unsigned short*)wsb;                // 8 MB
    float* a_self  = (float*)(wsb + (size_t)BATCH * NN * HH * 2);
    float* a_neigh = a_self + (size_t)BATCH * NN;

    gat_hidden<<<(BATCH * NN) / NODES, 128, 0, stream>>>(
        X, W, Wself, Wneigh, g, a_self, a_neigh);
    gat_attend<<<512, 512, 0, stream>>>(
        adj, mask, g, a_self, a_neigh, bvec, out);
}